// Round 12
// baseline (1148.291 us; speedup 1.0000x reference)
//
#include <hip/hip_runtime.h>
#include <math.h>

#define BB 4
#define TT 2048
#define DD 1024
#define HH 128
#define EPSF 1e-6f
#define BT (BB*TT)   // 8192
#define CC 128       // chunk length
#define NCH (TT/CC)  // 16 chunks per batch
#define NI (TT/2)    // 1024 double-steps

#define NWORK 248            // worker blocks in fused kernel
#define NTASKS (260 + 16*16) // 256 QV + 4 prefix + 16 chunks x (8 gram + 8 ochunk)
#define FLAGS_OFF ((size_t)20 << 20)   // byte offset of Flags in d_out

typedef float f32x2 __attribute__((ext_vector_type(2)));

struct Flags {
    int ticket;
    int qvcnt;
    int zdone[BB][NCH];
    int gramcnt[BB][NCH];
    int mpredone[BB][NCH];
};

// 8-lane butterfly sum, pure DPP/VALU (no DS pipe)
__device__ __forceinline__ float red8(float x) {
    x += __int_as_float(__builtin_amdgcn_mov_dpp(__float_as_int(x), 0xB1,  0xF, 0xF, true));
    x += __int_as_float(__builtin_amdgcn_mov_dpp(__float_as_int(x), 0x4E,  0xF, 0xF, true));
    x += __int_as_float(__builtin_amdgcn_mov_dpp(__float_as_int(x), 0x141, 0xF, 0xF, true));
    return x;
}
// 16-lane butterfly sum (adds ROW_MIRROR)
__device__ __forceinline__ float red16(float x) {
    x = red8(x);
    x += __int_as_float(__builtin_amdgcn_mov_dpp(__float_as_int(x), 0x140, 0xF, 0xF, true));
    return x;
}

// ---------------------------------------------------------------------------
// 512-thread projection tile: P[row0..row0+64][0..128) = x @ W^T + bias.
// mode 0: plain; mode 1: rn[row] epilogue (P=K); mode 2: s=q.k epilogue (P=Q).
// ---------------------------------------------------------------------------
__device__ __forceinline__ void proj512(
    const float* __restrict__ x, const float* __restrict__ W,
    const float* __restrict__ bias, float* __restrict__ P,
    int row0, int mode, float* __restrict__ aux,
    const float* __restrict__ Kmat,
    float (*xT)[68], float (*wT)[132])
{
    const int tid = threadIdx.x;
    const int tx = tid & 15;
    const int ty = tid >> 4;       // 0..31, rows ty*2 .. +2

    float acc[2][8];
    #pragma unroll
    for (int i = 0; i < 2; i++)
        #pragma unroll
        for (int j = 0; j < 8; j++) acc[i][j] = 0.f;

    for (int k0 = 0; k0 < DD; k0 += 32) {
        {   int r = tid >> 3, cg = tid & 7;
            float4 v = *(const float4*)(x + (size_t)(row0 + r) * DD + k0 + cg * 4);
            xT[cg*4+0][r] = v.x; xT[cg*4+1][r] = v.y;
            xT[cg*4+2][r] = v.z; xT[cg*4+3][r] = v.w;
        }
        #pragma unroll
        for (int l = 0; l < 2; l++) {
            int f = tid + l * 512;
            int h = f >> 3, cg = f & 7;
            float4 v = *(const float4*)(W + (size_t)h * DD + k0 + cg * 4);
            wT[cg*4+0][h] = v.x; wT[cg*4+1][h] = v.y;
            wT[cg*4+2][h] = v.z; wT[cg*4+3][h] = v.w;
        }
        __syncthreads();
        #pragma unroll
        for (int kk = 0; kk < 32; kk++) {
            float2 xv = *(const float2*)&xT[kk][ty * 2];
            float4 w0 = *(const float4*)&wT[kk][tx * 8];
            float4 w1 = *(const float4*)&wT[kk][tx * 8 + 4];
            float xa[2] = {xv.x, xv.y};
            float wa[8] = {w0.x, w0.y, w0.z, w0.w, w1.x, w1.y, w1.z, w1.w};
            #pragma unroll
            for (int i = 0; i < 2; i++)
                #pragma unroll
                for (int j = 0; j < 8; j++)
                    acc[i][j] += xa[i] * wa[j];
        }
        __syncthreads();
    }

    #pragma unroll
    for (int i = 0; i < 2; i++) {
        int row = row0 + ty * 2 + i;
        #pragma unroll
        for (int j = 0; j < 8; j++) acc[i][j] += bias[tx * 8 + j];
        float4 o0 = {acc[i][0], acc[i][1], acc[i][2], acc[i][3]};
        float4 o1 = {acc[i][4], acc[i][5], acc[i][6], acc[i][7]};
        *(float4*)(P + (size_t)row * HH + tx * 8)     = o0;
        *(float4*)(P + (size_t)row * HH + tx * 8 + 4) = o1;
    }

    if (mode == 1) {                 // rn = 1/(||k|| + eps)
        #pragma unroll
        for (int i = 0; i < 2; i++) {
            float p = 0.f;
            #pragma unroll
            for (int j = 0; j < 8; j++) p += acc[i][j] * acc[i][j];
            p = red16(p);
            if (tx == 0) aux[row0 + ty * 2 + i] = 1.0f / (sqrtf(p) + EPSF);
        }
    } else if (mode == 2) {          // s = q . k
        #pragma unroll
        for (int i = 0; i < 2; i++) {
            int row = row0 + ty * 2 + i;
            float4 ka = *(const float4*)(Kmat + (size_t)row * HH + tx * 8);
            float4 kb = *(const float4*)(Kmat + (size_t)row * HH + tx * 8 + 4);
            float p = acc[i][0]*ka.x + acc[i][1]*ka.y + acc[i][2]*ka.z + acc[i][3]*ka.w
                    + acc[i][4]*kb.x + acc[i][5]*kb.y + acc[i][6]*kb.z + acc[i][7]*kb.w;
            p = red16(p);
            if (tx == 0) aux[row] = p;
        }
    }
}

// K projection + rn epilogue (precedes the fused kernel).
__global__ __launch_bounds__(512) void projk_kernel(
    const float* __restrict__ x, const float* __restrict__ Wk,
    const float* __restrict__ bk, float* __restrict__ K,
    float* __restrict__ rn)
{
    __shared__ float xT[32][68];
    __shared__ float wT[32][132];
    proj512(x, Wk, bk, K, blockIdx.x * 64, 1, rn, nullptr, xT, wT);
}

// ---------------------------------------------------------------------------
// Worker task bodies (512 threads each).
// ---------------------------------------------------------------------------
// G[b][c] = V_chunk^T @ (diag(s) Z_chunk), rows r0..r0+64 of HxH.
__device__ void gram512(
    const float* __restrict__ V, const float* __restrict__ Z,
    const float* __restrict__ Sarr, float* __restrict__ G,
    int bi, int r0, float (*vT)[68], float (*aT)[132])
{
    const float* Vc = V + (size_t)bi * CC * HH;
    const float* Zc = Z + (size_t)bi * CC * HH;
    const float* Sc = Sarr + (size_t)bi * CC;
    const int tid = threadIdx.x;
    const int tx = tid & 15, ty = tid >> 4;

    float acc[2][8];
    #pragma unroll
    for (int i = 0; i < 2; i++)
        #pragma unroll
        for (int j = 0; j < 8; j++) acc[i][j] = 0.f;

    for (int s0 = 0; s0 < CC; s0 += 32) {
        {   int sr = tid >> 4, rc = tid & 15;
            float4 v = *(const float4*)(Vc + (size_t)(s0 + sr) * HH + r0 + rc * 4);
            *(float4*)&vT[sr][rc * 4] = v;
        }
        #pragma unroll
        for (int l = 0; l < 2; l++) {
            int f = tid + l * 512;
            int sr = f >> 5, cc = f & 31;
            float sv = Sc[s0 + sr];
            float4 v = *(const float4*)(Zc + (size_t)(s0 + sr) * HH + cc * 4);
            v.x *= sv; v.y *= sv; v.z *= sv; v.w *= sv;
            *(float4*)&aT[sr][cc * 4] = v;
        }
        __syncthreads();
        #pragma unroll
        for (int ss = 0; ss < 32; ss++) {
            float2 vv = *(const float2*)&vT[ss][ty * 2];
            float4 a0 = *(const float4*)&aT[ss][tx * 8];
            float4 a1 = *(const float4*)&aT[ss][tx * 8 + 4];
            float va[2] = {vv.x, vv.y};
            float aa[8] = {a0.x, a0.y, a0.z, a0.w, a1.x, a1.y, a1.z, a1.w};
            #pragma unroll
            for (int i = 0; i < 2; i++)
                #pragma unroll
                for (int j = 0; j < 8; j++)
                    acc[i][j] += va[i] * aa[j];
        }
        __syncthreads();
    }

    #pragma unroll
    for (int i = 0; i < 2; i++) {
        float* gp = G + ((size_t)bi * HH + r0 + ty * 2 + i) * HH + tx * 8;
        float4 o0 = {acc[i][0], acc[i][1], acc[i][2], acc[i][3]};
        float4 o1 = {acc[i][4], acc[i][5], acc[i][6], acc[i][7]};
        *(float4*)gp       = o0;
        *(float4*)(gp + 4) = o1;
    }
}

// O rows t0..t0+64 of chunk bi: Q Mpre^T + tril(Q (sZ)^T) V.
__device__ void ochunk512(
    const float* __restrict__ Q, const float* __restrict__ Z,
    const float* __restrict__ Sarr, const float* __restrict__ V,
    const float* __restrict__ Mpre, float* __restrict__ O,
    int bi, int t0, float (*shA)[68], float (*shB)[132], float (*shS)[132])
{
    const float* Qc = Q    + (size_t)bi * CC * HH;
    const float* Zc = Z    + (size_t)bi * CC * HH;
    const float* Vc = V    + (size_t)bi * CC * HH;
    const float* Sc = Sarr + (size_t)bi * CC;
    const float* Mp = Mpre + (size_t)bi * HH * HH;
    float*       Oc = O    + (size_t)bi * CC * HH;

    const int tid = threadIdx.x;
    const int tx = tid & 15, ty = tid >> 4;

    float acc[2][8];

    // ---- phase 1: S = tril(Q (sZ)^T)
    #pragma unroll
    for (int i = 0; i < 2; i++)
        #pragma unroll
        for (int j = 0; j < 8; j++) acc[i][j] = 0.f;
    for (int k0 = 0; k0 < HH; k0 += 32) {
        {   int r = tid >> 3, cg = tid & 7;
            float4 v = *(const float4*)(Qc + (size_t)(t0 + r) * HH + k0 + cg * 4);
            shA[cg*4+0][r] = v.x; shA[cg*4+1][r] = v.y;
            shA[cg*4+2][r] = v.z; shA[cg*4+3][r] = v.w;
        }
        #pragma unroll
        for (int l = 0; l < 2; l++) {
            int f = tid + l * 512;
            int sr = f >> 3, cg = f & 7;
            float sv = Sc[sr];
            float4 v = *(const float4*)(Zc + (size_t)sr * HH + k0 + cg * 4);
            shB[cg*4+0][sr] = v.x * sv; shB[cg*4+1][sr] = v.y * sv;
            shB[cg*4+2][sr] = v.z * sv; shB[cg*4+3][sr] = v.w * sv;
        }
        __syncthreads();
        #pragma unroll
        for (int kk = 0; kk < 32; kk++) {
            float2 xv = *(const float2*)&shA[kk][ty * 2];
            float4 w0 = *(const float4*)&shB[kk][tx * 8];
            float4 w1 = *(const float4*)&shB[kk][tx * 8 + 4];
            float xa[2] = {xv.x, xv.y};
            float wa[8] = {w0.x, w0.y, w0.z, w0.w, w1.x, w1.y, w1.z, w1.w};
            #pragma unroll
            for (int i = 0; i < 2; i++)
                #pragma unroll
                for (int j = 0; j < 8; j++)
                    acc[i][j] += xa[i] * wa[j];
        }
        __syncthreads();
    }
    #pragma unroll
    for (int i = 0; i < 2; i++) {
        int tl = t0 + ty * 2 + i;
        float m[8];
        #pragma unroll
        for (int j = 0; j < 8; j++)
            m[j] = (tx * 8 + j <= tl) ? acc[i][j] : 0.f;
        float4 o0 = {m[0], m[1], m[2], m[3]};
        float4 o1 = {m[4], m[5], m[6], m[7]};
        *(float4*)&shS[ty*2+i][tx*8]     = o0;
        *(float4*)&shS[ty*2+i][tx*8 + 4] = o1;
    }

    // ---- phase 2: acc = Q @ Mpre^T
    #pragma unroll
    for (int i = 0; i < 2; i++)
        #pragma unroll
        for (int j = 0; j < 8; j++) acc[i][j] = 0.f;
    for (int k0 = 0; k0 < HH; k0 += 32) {
        {   int r = tid >> 3, cg = tid & 7;
            float4 v = *(const float4*)(Qc + (size_t)(t0 + r) * HH + k0 + cg * 4);
            shA[cg*4+0][r] = v.x; shA[cg*4+1][r] = v.y;
            shA[cg*4+2][r] = v.z; shA[cg*4+3][r] = v.w;
        }
        #pragma unroll
        for (int l = 0; l < 2; l++) {
            int f = tid + l * 512;
            int h = f >> 3, cg = f & 7;
            float4 v = *(const float4*)(Mp + (size_t)h * HH + k0 + cg * 4);
            shB[cg*4+0][h] = v.x; shB[cg*4+1][h] = v.y;
            shB[cg*4+2][h] = v.z; shB[cg*4+3][h] = v.w;
        }
        __syncthreads();
        #pragma unroll
        for (int kk = 0; kk < 32; kk++) {
            float2 xv = *(const float2*)&shA[kk][ty * 2];
            float4 w0 = *(const float4*)&shB[kk][tx * 8];
            float4 w1 = *(const float4*)&shB[kk][tx * 8 + 4];
            float xa[2] = {xv.x, xv.y};
            float wa[8] = {w0.x, w0.y, w0.z, w0.w, w1.x, w1.y, w1.z, w1.w};
            #pragma unroll
            for (int i = 0; i < 2; i++)
                #pragma unroll
                for (int j = 0; j < 8; j++)
                    acc[i][j] += xa[i] * wa[j];
        }
        __syncthreads();
    }

    // ---- phase 3: acc += S @ V
    for (int s0 = 0; s0 < CC; s0 += 32) {
        #pragma unroll
        for (int l = 0; l < 2; l++) {
            int f = tid + l * 512;
            int sr = f >> 5, cc = f & 31;
            float4 v = *(const float4*)(Vc + (size_t)(s0 + sr) * HH + cc * 4);
            *(float4*)&shB[sr][cc * 4] = v;
        }
        __syncthreads();
        #pragma unroll
        for (int ss = 0; ss < 32; ss++) {
            float4 w0 = *(const float4*)&shB[ss][tx * 8];
            float4 w1 = *(const float4*)&shB[ss][tx * 8 + 4];
            float wa[8] = {w0.x, w0.y, w0.z, w0.w, w1.x, w1.y, w1.z, w1.w};
            float sv[2] = {shS[ty*2][s0 + ss], shS[ty*2+1][s0 + ss]};
            #pragma unroll
            for (int i = 0; i < 2; i++)
                #pragma unroll
                for (int j = 0; j < 8; j++)
                    acc[i][j] += sv[i] * wa[j];
        }
        __syncthreads();
    }

    #pragma unroll
    for (int i = 0; i < 2; i++) {
        float* op = Oc + (size_t)(t0 + ty * 2 + i) * HH + tx * 8;
        float4 o0 = {acc[i][0], acc[i][1], acc[i][2], acc[i][3]};
        float4 o1 = {acc[i][4], acc[i][5], acc[i][6], acc[i][7]};
        *(float4*)op       = o0;
        *(float4*)(op + 4) = o1;
    }
}

// Incremental exclusive prefix for batch b (long-running task).
__device__ void prefix_task(int b, const float* __restrict__ G,
                            float* __restrict__ Mpre, Flags* fl)
{
    const int tid = threadIdx.x;
    float* mp0 = Mpre + (size_t)b * NCH * HH * HH;
    float4 zero = {0.f, 0.f, 0.f, 0.f};
    for (int idx = tid; idx < HH * HH / 4; idx += 512)
        ((float4*)mp0)[idx] = zero;
    __threadfence();
    __syncthreads();
    if (tid == 0) atomicExch(&fl->mpredone[b][0], 1);
    for (int c = 1; c < NCH; ++c) {
        if (tid == 0)
            while (atomicAdd(&fl->gramcnt[b][c-1], 0) < 2)
                __builtin_amdgcn_s_sleep(32);
        __syncthreads();
        __threadfence();
        const float* gp = G + ((size_t)b * NCH + (c-1)) * HH * HH;
        const float* mprev = Mpre + ((size_t)b * NCH + (c-1)) * HH * HH;
        float* mcur = Mpre + ((size_t)b * NCH + c) * HH * HH;
        for (int idx = tid; idx < HH * HH / 4; idx += 512) {
            float4 a = ((const float4*)mprev)[idx];
            float4 g = ((const float4*)gp)[idx];
            a.x += g.x; a.y += g.y; a.z += g.z; a.w += g.w;
            ((float4*)mcur)[idx] = a;
        }
        __threadfence();
        __syncthreads();
        if (tid == 0) atomicExch(&fl->mpredone[b][c], 1);
    }
}

// ---------------------------------------------------------------------------
// Fused kernel: blocks 0..3 = v8 scan (publishes per-chunk Z flags);
// blocks 4..251 = workers pulling {QV proj, prefix, gram, ochunk} tasks from
// an atomic ticket queue, gated on device-scope flags (G16 pattern:
// threadfence + device-scope atomics both sides).
// ---------------------------------------------------------------------------
__global__ __launch_bounds__(512, 1) void fused_kernel(
    const float* __restrict__ x,
    const float* __restrict__ Wq, const float* __restrict__ bq,
    const float* __restrict__ Wv, const float* __restrict__ bv,
    const float* __restrict__ K, const float* __restrict__ rn,
    float* __restrict__ Q, float* __restrict__ V,
    float* __restrict__ Sarr, float* __restrict__ Z,
    float* __restrict__ G, float* __restrict__ Mpre,
    float* __restrict__ O, Flags* fl)
{
    __shared__ float shA[32][68];
    __shared__ float shB[32][132];
    __shared__ float shS[64][132];
    __shared__ float Ybc[2][2][8 * 20];
    __shared__ float kst[2][2][8 * 20];
    __shared__ int sh_task;

    const int tid = threadIdx.x;

    if (blockIdx.x >= BB) {
        // ---------------- worker path: ticket-driven task loop
        for (;;) {
            __syncthreads();          // protect LDS + sh_task across tasks
            if (tid == 0) sh_task = atomicAdd(&fl->ticket, 1);
            __syncthreads();
            const int t = sh_task;
            if (t >= NTASKS) return;

            if (t < 256) {
                const int which = t >> 7, tile = t & 127;
                if (which == 0)
                    proj512(x, Wq, bq, Q, tile * 64, 2, Sarr, K, shA, shB);
                else
                    proj512(x, Wv, bv, V, tile * 64, 0, nullptr, nullptr, shA, shB);
                __threadfence();
                __syncthreads();
                if (tid == 0) atomicAdd(&fl->qvcnt, 1);
            } else if (t < 260) {
                prefix_task(t - 256, G, Mpre, fl);
            } else {
                const int tp = t - 260;
                const int c = tp >> 4, r = tp & 15;
                if (tid == 0)
                    while (atomicAdd(&fl->qvcnt, 0) < 256)
                        __builtin_amdgcn_s_sleep(32);
                __syncthreads();
                if (r < 8) {
                    const int bb = r >> 1, half = r & 1;
                    if (tid == 0)
                        while (atomicAdd(&fl->zdone[bb][c], 0) == 0)
                            __builtin_amdgcn_s_sleep(32);
                    __syncthreads();
                    __threadfence();
                    gram512(V, Z, Sarr, G, bb * NCH + c, half * 64, shA, shB);
                    __threadfence();
                    __syncthreads();
                    if (tid == 0) atomicAdd(&fl->gramcnt[bb][c], 1);
                } else {
                    const int bb = (r - 8) >> 1, half = (r - 8) & 1;
                    if (tid == 0) {
                        while (atomicAdd(&fl->zdone[bb][c], 0) == 0)
                            __builtin_amdgcn_s_sleep(32);
                        while (atomicAdd(&fl->mpredone[bb][c], 0) == 0)
                            __builtin_amdgcn_s_sleep(32);
                    }
                    __syncthreads();
                    __threadfence();
                    ochunk512(Q, Z, Sarr, V, Mpre, O, bb * NCH + c, half * 64,
                              shA, shB, shS);
                }
            }
        }
    }

    // ---------------- scan path (v8 rank-2 A-only; verified @832us)
    const int b   = blockIdx.x;
    const int r2  = tid >> 3;
    const int o8  = tid & 7;
    const int c0  = o8 * 16;
    const int r0  = 2 * r2, r1 = r0 + 1;

    f32x2 Ar0[8], Ar1[8];
    #pragma unroll
    for (int j = 0; j < 8; j++) {
        Ar0[j].x = (c0 + 2*j     == r0) ? 1.f : 0.f;
        Ar0[j].y = (c0 + 2*j + 1 == r0) ? 1.f : 0.f;
        Ar1[j].x = (c0 + 2*j     == r1) ? 1.f : 0.f;
        Ar1[j].y = (c0 + 2*j + 1 == r1) ? 1.f : 0.f;
    }

    const float* Kb = K + (size_t)b * TT * HH;
    float*       Zb = Z + (size_t)b * TT * HH;
    const float* rn_b = rn + (size_t)b * TT;

    const int woff = (r0 >> 4) * 20 + (r0 & 15);
    const int roff = o8 * 20;

    const bool ldr    = tid < 64;
    const int  whichk = tid >> 5;
    const int  l32    = tid & 31;
    const int  lpoff  = (l32 >> 2) * 20 + (l32 & 3) * 4;   // v8 8x20 mapping

    float4 pld = {0.f, 0.f, 0.f, 0.f};
    if (ldr) {
        float4 d0 = *(const float4*)(Kb + (size_t)whichk * HH + l32 * 4);
        *(float4*)&kst[0][whichk][lpoff] = d0;
        pld = *(const float4*)(Kb + (size_t)(2 + whichk) * HH + l32 * 4);
    }
    float2 rs_cur = ((const float2*)rn_b)[0];
    float2 rs_nxt = ((const float2*)rn_b)[1];
    __syncthreads();

    f32x2 k1[8], k2[8];
    #pragma unroll
    for (int j = 0; j < 4; j++) {
        float4 t1 = *(const float4*)&kst[0][0][roff + 4 * j];
        float4 t2 = *(const float4*)&kst[0][1][roff + 4 * j];
        k1[2*j] = (f32x2){t1.x, t1.y}; k1[2*j+1] = (f32x2){t1.z, t1.w};
        k2[2*j] = (f32x2){t2.x, t2.y}; k2[2*j+1] = (f32x2){t2.z, t2.w};
    }

    for (int i = 0; i < NI; ++i) {
        const int yb = i & 1;
        const int nk = (i + 1) & 1;

        f32x2 y10 = {0,0}, y11 = {0,0}, y20 = {0,0}, y21 = {0,0};
        #pragma unroll
        for (int j = 0; j < 8; j++) {
            y10 += Ar0[j] * k1[j];
            y11 += Ar1[j] * k1[j];
            y20 += Ar0[j] * k2[j];
            y21 += Ar1[j] * k2[j];
        }
        float y1r0 = red8(y10.x + y10.y);
        float y1r1 = red8(y11.x + y11.y);
        float y2r0 = red8(y20.x + y20.y);
        float y2r1 = red8(y21.x + y21.y);
        if (o8 == 0) {
            *(float2*)&Ybc[yb][0][woff] = make_float2(y1r0, y1r1);
            *(float2*)&Ybc[yb][1][woff] = make_float2(y2r0, y2r1);
        }

        if (ldr && i + 1 < NI) {
            *(float4*)&kst[nk][whichk][lpoff] = pld;
            if (i + 2 < NI)
                pld = *(const float4*)(Kb + (size_t)(2*(i+2) + whichk) * HH + l32 * 4);
        }

        __syncthreads();

        f32x2 av1[8], av2[8];
        #pragma unroll
        for (int j = 0; j < 4; j++) {
            float4 t1 = *(const float4*)&Ybc[yb][0][roff + 4 * j];
            float4 t2 = *(const float4*)&Ybc[yb][1][roff + 4 * j];
            av1[2*j] = (f32x2){t1.x, t1.y}; av1[2*j+1] = (f32x2){t1.z, t1.w};
            av2[2*j] = (f32x2){t2.x, t2.y}; av2[2*j+1] = (f32x2){t2.z, t2.w};
        }

        f32x2 e11v = {0,0}, e21v = {0,0}, e22v = {0,0};
        #pragma unroll
        for (int j = 0; j < 8; j++) {
            e11v += av1[j] * k1[j];
            e21v += av1[j] * k2[j];
            e22v += av2[j] * k2[j];
        }
        float e11 = red8(e11v.x + e11v.y);
        float e21 = red8(e21v.x + e21v.y);
        float e22 = red8(e22v.x + e22v.y);

        #pragma unroll
        for (int j = 0; j < 4; j++) {
            float4 t1 = *(const float4*)&kst[nk][0][roff + 4 * j];
            float4 t2 = *(const float4*)&kst[nk][1][roff + 4 * j];
            k1[2*j] = (f32x2){t1.x, t1.y}; k1[2*j+1] = (f32x2){t1.z, t1.w};
            k2[2*j] = (f32x2){t2.x, t2.y}; k2[2*j+1] = (f32x2){t2.z, t2.w};
        }

        const float rn1 = rs_cur.x, rn2 = rs_cur.y;
        const float rn1sq = rn1 * rn1;
        const float rn2sq = rn2 * rn2;
        const float i1   = __builtin_amdgcn_rcpf(1.0f + rn1sq * e11);
        const float beta = rn1sq * e21 * i1;
        const float i2   = __builtin_amdgcn_rcpf(1.0f + rn2sq * (e22 - beta * e21));
        const float p2r0 = y2r0 - beta * y1r0;
        const float p2r1 = y2r1 - beta * y1r1;
        const float za1  = rn1 * i1;
        const float za2  = rn2 * i2;
        if (o8 == 0) {
            *(float2*)(Zb + (size_t)(2*i)     * HH + r0) =
                make_float2(za1 * y1r0, za1 * y1r1);
            *(float2*)(Zb + (size_t)(2*i + 1) * HH + r0) =
                make_float2(za2 * p2r0, za2 * p2r1);
        }

        const float cA1 = rn1sq * i1, cA2 = rn2sq * i2;
        const f32x2 u10 = {cA1 * y1r0, cA1 * y1r0};
        const f32x2 u11 = {cA1 * y1r1, cA1 * y1r1};
        const f32x2 u20 = {cA2 * p2r0, cA2 * p2r0};
        const f32x2 u21 = {cA2 * p2r1, cA2 * p2r1};
        const f32x2 bbv = {beta, beta};
        #pragma unroll
        for (int j = 0; j < 8; j++) {
            f32x2 pp = av2[j] - bbv * av1[j];
            Ar0[j] = Ar0[j] - u10 * av1[j] - u20 * pp;
            Ar1[j] = Ar1[j] - u11 * av1[j] - u21 * pp;
        }

        rs_cur = rs_nxt;
        if (i + 2 < NI) rs_nxt = ((const float2*)rn_b)[i + 2];

        // publish Z chunk flag (chunk = i>>6 complete at i%64==63)
        if ((i & 63) == 63) {
            __threadfence();
            __syncthreads();
            if (tid == 0) atomicExch(&fl->zdone[b][i >> 6], 1);
        }
    }
}

// ---------------------------------------------------------------------------
// Output: out[bt][d] = sum_h O[bt][h] * Wo[d][h] + bo[d]
// ---------------------------------------------------------------------------
__global__ __launch_bounds__(256) void out_kernel(
    const float* __restrict__ O, const float* __restrict__ Wo,
    const float* __restrict__ bo, float* __restrict__ out)
{
    const int row0 = blockIdx.x * 64;
    const int d0   = blockIdx.y * 128;

    __shared__ float oT[32][68];
    __shared__ float woT[32][132];

    const int tid = threadIdx.x;
    const int tx = tid & 15;
    const int ty = tid >> 4;

    float acc[4][8];
    #pragma unroll
    for (int i = 0; i < 4; i++)
        #pragma unroll
        for (int j = 0; j < 8; j++) acc[i][j] = 0.f;

    for (int k0 = 0; k0 < HH; k0 += 32) {
        #pragma unroll
        for (int l = 0; l < 2; l++) {
            int f = tid + l * 256;
            int r = f >> 3;
            int cg = f & 7;
            float4 v = *(const float4*)(O + (size_t)(row0 + r) * HH + k0 + cg * 4);
            oT[cg*4+0][r] = v.x; oT[cg*4+1][r] = v.y;
            oT[cg*4+2][r] = v.z; oT[cg*4+3][r] = v.w;
        }
        #pragma unroll
        for (int l = 0; l < 4; l++) {
            int f = tid + l * 256;
            int d = f >> 3;
            int cg = f & 7;
            float4 v = *(const float4*)(Wo + (size_t)(d0 + d) * HH + k0 + cg * 4);
            woT[cg*4+0][d] = v.x; woT[cg*4+1][d] = v.y;
            woT[cg*4+2][d] = v.z; woT[cg*4+3][d] = v.w;
        }
        __syncthreads();
        #pragma unroll
        for (int kk = 0; kk < 32; kk++) {
            float4 ov = *(const float4*)&oT[kk][ty * 4];
            float4 w0 = *(const float4*)&woT[kk][tx * 8];
            float4 w1 = *(const float4*)&woT[kk][tx * 8 + 4];
            float oa[4] = {ov.x, ov.y, ov.z, ov.w};
            float wa[8] = {w0.x, w0.y, w0.z, w0.w, w1.x, w1.y, w1.z, w1.w};
            #pragma unroll
            for (int i = 0; i < 4; i++)
                #pragma unroll
                for (int j = 0; j < 8; j++)
                    acc[i][j] += oa[i] * wa[j];
        }
        __syncthreads();
    }

    #pragma unroll
    for (int i = 0; i < 4; i++) {
        int row = row0 + ty * 4 + i;
        #pragma unroll
        for (int j = 0; j < 8; j++) acc[i][j] += bo[d0 + tx * 8 + j];
        float4 o0 = {acc[i][0], acc[i][1], acc[i][2], acc[i][3]};
        float4 o1 = {acc[i][4], acc[i][5], acc[i][6], acc[i][7]};
        *(float4*)(out + (size_t)row * DD + d0 + tx * 8)     = o0;
        *(float4*)(out + (size_t)row * DD + d0 + tx * 8 + 4) = o1;
    }
}

extern "C" void kernel_launch(void* const* d_in, const int* in_sizes, int n_in,
                              void* d_out, int out_size, void* d_ws, size_t ws_size,
                              hipStream_t stream) {
    const float* x  = (const float*)d_in[0];
    const float* Wq = (const float*)d_in[1];
    const float* bq = (const float*)d_in[2];
    const float* Wk = (const float*)d_in[3];
    const float* bk = (const float*)d_in[4];
    const float* Wv = (const float*)d_in[5];
    const float* bv = (const float*)d_in[6];
    const float* Wo = (const float*)d_in[7];
    const float* bo = (const float*)d_in[8];
    float* out = (float*)d_out;

    float* ws = (float*)d_ws;
    float* Q = ws;
    float* K = ws + (size_t)BT * HH;
    float* V = ws + (size_t)2 * BT * HH;
    float* O = ws + (size_t)3 * BT * HH;

    // scratch in d_out (32 MB), all dead before out_kernel writes it:
    //   rn @0 (32KB) | s @32KB | Z @1MB (4MB) | G @8MB (4MB) | Mpre @12MB (4MB)
    //   Flags @20MB (zeroed per launch below)
    float* db   = (float*)d_out;
    float* rn   = db;
    float* Sarr = db + BT;
    float* Z    = db + (1u << 18);
    float* G    = db + (1u << 21);
    float* Mpre = db + 3u * (1u << 20);
    Flags* fl   = (Flags*)((char*)d_out + FLAGS_OFF);

    // zero pipeline flags (graph-capturable stream op; replay-safe)
    hipMemsetAsync((void*)fl, 0, sizeof(Flags), stream);

    // 1. K projection (+rn) — the scan's only dependency
    projk_kernel<<<BT / 64, 512, 0, stream>>>(x, Wk, bk, K, rn);

    // 2. fused pipeline: 4 scan blocks + 248 workers (QV, prefix, gram, ochunk)
    fused_kernel<<<BB + NWORK, 512, 0, stream>>>(
        x, Wq, bq, Wv, bv, K, rn, Q, V, Sarr, Z, G, Mpre, O, fl);

    // 3. output projection
    dim3 ogrid(BT / 64, DD / 128);
    out_kernel<<<ogrid, 256, 0, stream>>>(O, Wo, bo, out);
}

// Round 13
// 1040.213 us; speedup vs baseline: 1.1039x; 1.1039x over previous
//
#include <hip/hip_runtime.h>
#include <math.h>

#define BB 4
#define TT 2048
#define DD 1024
#define HH 128
#define EPSF 1e-6f
#define BT (BB*TT)   // 8192
#define CC 128       // chunk length
#define NCH (TT/CC)  // 16 chunks per batch
#define NI (TT/2)    // 1024 double-steps

typedef float f32x2 __attribute__((ext_vector_type(2)));

// 8-lane butterfly sum, pure DPP/VALU (no DS pipe)
__device__ __forceinline__ float red8(float x) {
    x += __int_as_float(__builtin_amdgcn_mov_dpp(__float_as_int(x), 0xB1,  0xF, 0xF, true));
    x += __int_as_float(__builtin_amdgcn_mov_dpp(__float_as_int(x), 0x4E,  0xF, 0xF, true));
    x += __int_as_float(__builtin_amdgcn_mov_dpp(__float_as_int(x), 0x141, 0xF, 0xF, true));
    return x;
}
// 16-lane butterfly sum (adds ROW_MIRROR)
__device__ __forceinline__ float red16(float x) {
    x = red8(x);
    x += __int_as_float(__builtin_amdgcn_mov_dpp(__float_as_int(x), 0x140, 0xF, 0xF, true));
    return x;
}

// ---------------------------------------------------------------------------
// 512-thread projection tile (worker path of fused kernel, UNCHANGED v12):
// P[row0..row0+64][0..128) = x @ W^T + bias.
// mode 0: plain; mode 2: s=q.k epilogue (P=Q).
// ---------------------------------------------------------------------------
__device__ __forceinline__ void proj512(
    const float* __restrict__ x, const float* __restrict__ W,
    const float* __restrict__ bias, float* __restrict__ P,
    int row0, int mode, float* __restrict__ aux,
    const float* __restrict__ Kmat)
{
    __shared__ float xT[32][68];
    __shared__ float wT[32][132];

    const int tid = threadIdx.x;
    const int tx = tid & 15;
    const int ty = tid >> 4;       // 0..31, rows ty*2 .. +2

    float acc[2][8];
    #pragma unroll
    for (int i = 0; i < 2; i++)
        #pragma unroll
        for (int j = 0; j < 8; j++) acc[i][j] = 0.f;

    for (int k0 = 0; k0 < DD; k0 += 32) {
        {   int r = tid >> 3, cg = tid & 7;
            float4 v = *(const float4*)(x + (size_t)(row0 + r) * DD + k0 + cg * 4);
            xT[cg*4+0][r] = v.x; xT[cg*4+1][r] = v.y;
            xT[cg*4+2][r] = v.z; xT[cg*4+3][r] = v.w;
        }
        #pragma unroll
        for (int l = 0; l < 2; l++) {
            int f = tid + l * 512;
            int h = f >> 3, cg = f & 7;
            float4 v = *(const float4*)(W + (size_t)h * DD + k0 + cg * 4);
            wT[cg*4+0][h] = v.x; wT[cg*4+1][h] = v.y;
            wT[cg*4+2][h] = v.z; wT[cg*4+3][h] = v.w;
        }
        __syncthreads();
        #pragma unroll
        for (int kk = 0; kk < 32; kk++) {
            float2 xv = *(const float2*)&xT[kk][ty * 2];
            float4 w0 = *(const float4*)&wT[kk][tx * 8];
            float4 w1 = *(const float4*)&wT[kk][tx * 8 + 4];
            float xa[2] = {xv.x, xv.y};
            float wa[8] = {w0.x, w0.y, w0.z, w0.w, w1.x, w1.y, w1.z, w1.w};
            #pragma unroll
            for (int i = 0; i < 2; i++)
                #pragma unroll
                for (int j = 0; j < 8; j++)
                    acc[i][j] += xa[i] * wa[j];
        }
        __syncthreads();
    }

    #pragma unroll
    for (int i = 0; i < 2; i++) {
        int row = row0 + ty * 2 + i;
        #pragma unroll
        for (int j = 0; j < 8; j++) acc[i][j] += bias[tx * 8 + j];
        float4 o0 = {acc[i][0], acc[i][1], acc[i][2], acc[i][3]};
        float4 o1 = {acc[i][4], acc[i][5], acc[i][6], acc[i][7]};
        *(float4*)(P + (size_t)row * HH + tx * 8)     = o0;
        *(float4*)(P + (size_t)row * HH + tx * 8 + 4) = o1;
    }

    if (mode == 2) {                 // s = q . k
        #pragma unroll
        for (int i = 0; i < 2; i++) {
            int row = row0 + ty * 2 + i;
            float4 ka = *(const float4*)(Kmat + (size_t)row * HH + tx * 8);
            float4 kb = *(const float4*)(Kmat + (size_t)row * HH + tx * 8 + 4);
            float p = acc[i][0]*ka.x + acc[i][1]*ka.y + acc[i][2]*ka.z + acc[i][3]*ka.w
                    + acc[i][4]*kb.x + acc[i][5]*kb.y + acc[i][6]*kb.z + acc[i][7]*kb.w;
            p = red16(p);
            if (tx == 0) aux[row] = p;
        }
    }
}

// ---------------------------------------------------------------------------
// K projection + rn epilogue, FULL-GPU: 256 blocks x 256 threads, 32-row tiles.
// ---------------------------------------------------------------------------
__global__ __launch_bounds__(256) void projk_kernel(
    const float* __restrict__ x, const float* __restrict__ Wk,
    const float* __restrict__ bk, float* __restrict__ K,
    float* __restrict__ rn)
{
    const int row0 = blockIdx.x * 32;

    __shared__ float xT[32][36];
    __shared__ float wT[32][132];

    const int tid = threadIdx.x;
    const int tx = tid & 15;
    const int ty = tid >> 4;       // 0..15, rows ty*2..+2

    float acc[2][8];
    #pragma unroll
    for (int i = 0; i < 2; i++)
        #pragma unroll
        for (int j = 0; j < 8; j++) acc[i][j] = 0.f;

    for (int k0 = 0; k0 < DD; k0 += 32) {
        {   int r = tid >> 3, cg = tid & 7;   // 32 rows x 8 f4
            float4 v = *(const float4*)(x + (size_t)(row0 + r) * DD + k0 + cg * 4);
            xT[cg*4+0][r] = v.x; xT[cg*4+1][r] = v.y;
            xT[cg*4+2][r] = v.z; xT[cg*4+3][r] = v.w;
        }
        #pragma unroll
        for (int l = 0; l < 4; l++) {          // 128 h x 8 f4
            int f = tid + l * 256;
            int h = f >> 3, cg = f & 7;
            float4 v = *(const float4*)(Wk + (size_t)h * DD + k0 + cg * 4);
            wT[cg*4+0][h] = v.x; wT[cg*4+1][h] = v.y;
            wT[cg*4+2][h] = v.z; wT[cg*4+3][h] = v.w;
        }
        __syncthreads();
        #pragma unroll
        for (int kk = 0; kk < 32; kk++) {
            float2 xv = *(const float2*)&xT[kk][ty * 2];
            float4 w0 = *(const float4*)&wT[kk][tx * 8];
            float4 w1 = *(const float4*)&wT[kk][tx * 8 + 4];
            float xa[2] = {xv.x, xv.y};
            float wa[8] = {w0.x, w0.y, w0.z, w0.w, w1.x, w1.y, w1.z, w1.w};
            #pragma unroll
            for (int i = 0; i < 2; i++)
                #pragma unroll
                for (int j = 0; j < 8; j++)
                    acc[i][j] += xa[i] * wa[j];
        }
        __syncthreads();
    }

    #pragma unroll
    for (int i = 0; i < 2; i++) {
        int row = row0 + ty * 2 + i;
        #pragma unroll
        for (int j = 0; j < 8; j++) acc[i][j] += bk[tx * 8 + j];
        float4 o0 = {acc[i][0], acc[i][1], acc[i][2], acc[i][3]};
        float4 o1 = {acc[i][4], acc[i][5], acc[i][6], acc[i][7]};
        *(float4*)(K + (size_t)row * HH + tx * 8)     = o0;
        *(float4*)(K + (size_t)row * HH + tx * 8 + 4) = o1;
        float p = 0.f;
        #pragma unroll
        for (int j = 0; j < 8; j++) p += acc[i][j] * acc[i][j];
        p = red16(p);
        if (tx == 0) rn[row] = 1.0f / (sqrtf(p) + EPSF);
    }
}

// ---------------------------------------------------------------------------
// Fused kernel (UNCHANGED from v12, verified 813us): blocks 0..3 = v8 scan;
// blocks 4..255 = Q (+s) and V projections on otherwise-idle CUs.
// ---------------------------------------------------------------------------
__global__ __launch_bounds__(512, 1) void fused_kernel(
    const float* __restrict__ x,
    const float* __restrict__ Wq, const float* __restrict__ bq,
    const float* __restrict__ Wv, const float* __restrict__ bv,
    const float* __restrict__ K, const float* __restrict__ rn,
    float* __restrict__ Q, float* __restrict__ V,
    float* __restrict__ Sarr, float* __restrict__ Z)
{
    __shared__ float Ybc[2][2][8 * 20];   // scan: [buf][y1/y2], padded
    __shared__ float kst[2][2][8 * 20];   // scan: [buf][k1/k2], padded

    if (blockIdx.x >= BB) {
        const int wb = blockIdx.x - BB;          // 0..251
        for (int t = wb; t < 256; t += 252) {
            const int which = t >> 7;            // 0 = Q, 1 = V
            const int tile  = t & 127;
            if (which == 0)
                proj512(x, Wq, bq, Q, tile * 64, 2, Sarr, K);
            else
                proj512(x, Wv, bv, V, tile * 64, 0, nullptr, nullptr);
        }
        return;
    }

    const int b   = blockIdx.x;
    const int tid = threadIdx.x;
    const int r2  = tid >> 3;
    const int o8  = tid & 7;
    const int c0  = o8 * 16;
    const int r0  = 2 * r2, r1 = r0 + 1;

    f32x2 Ar0[8], Ar1[8];
    #pragma unroll
    for (int j = 0; j < 8; j++) {
        Ar0[j].x = (c0 + 2*j     == r0) ? 1.f : 0.f;
        Ar0[j].y = (c0 + 2*j + 1 == r0) ? 1.f : 0.f;
        Ar1[j].x = (c0 + 2*j     == r1) ? 1.f : 0.f;
        Ar1[j].y = (c0 + 2*j + 1 == r1) ? 1.f : 0.f;
    }

    const float* Kb = K + (size_t)b * TT * HH;
    float*       Zb = Z + (size_t)b * TT * HH;
    const float* rn_b = rn + (size_t)b * TT;

    const int woff = (r0 >> 4) * 20 + (r0 & 15);
    const int roff = o8 * 20;

    const bool ldr    = tid < 64;
    const int  whichk = tid >> 5;
    const int  l32    = tid & 31;
    const int  lpoff  = (l32 >> 2) * 20 + (l32 & 3) * 4;   // v8 8x20 mapping

    float4 pld = {0.f, 0.f, 0.f, 0.f};
    if (ldr) {
        float4 d0 = *(const float4*)(Kb + (size_t)whichk * HH + l32 * 4);
        *(float4*)&kst[0][whichk][lpoff] = d0;
        pld = *(const float4*)(Kb + (size_t)(2 + whichk) * HH + l32 * 4);
    }
    float2 rs_cur = ((const float2*)rn_b)[0];
    float2 rs_nxt = ((const float2*)rn_b)[1];
    __syncthreads();

    f32x2 k1[8], k2[8];
    #pragma unroll
    for (int j = 0; j < 4; j++) {
        float4 t1 = *(const float4*)&kst[0][0][roff + 4 * j];
        float4 t2 = *(const float4*)&kst[0][1][roff + 4 * j];
        k1[2*j] = (f32x2){t1.x, t1.y}; k1[2*j+1] = (f32x2){t1.z, t1.w};
        k2[2*j] = (f32x2){t2.x, t2.y}; k2[2*j+1] = (f32x2){t2.z, t2.w};
    }

    for (int i = 0; i < NI; ++i) {
        const int yb = i & 1;
        const int nk = (i + 1) & 1;

        f32x2 y10 = {0,0}, y11 = {0,0}, y20 = {0,0}, y21 = {0,0};
        #pragma unroll
        for (int j = 0; j < 8; j++) {
            y10 += Ar0[j] * k1[j];
            y11 += Ar1[j] * k1[j];
            y20 += Ar0[j] * k2[j];
            y21 += Ar1[j] * k2[j];
        }
        float y1r0 = red8(y10.x + y10.y);
        float y1r1 = red8(y11.x + y11.y);
        float y2r0 = red8(y20.x + y20.y);
        float y2r1 = red8(y21.x + y21.y);
        if (o8 == 0) {
            *(float2*)&Ybc[yb][0][woff] = make_float2(y1r0, y1r1);
            *(float2*)&Ybc[yb][1][woff] = make_float2(y2r0, y2r1);
        }

        if (ldr && i + 1 < NI) {
            *(float4*)&kst[nk][whichk][lpoff] = pld;
            if (i + 2 < NI)
                pld = *(const float4*)(Kb + (size_t)(2*(i+2) + whichk) * HH + l32 * 4);
        }

        __syncthreads();

        f32x2 av1[8], av2[8];
        #pragma unroll
        for (int j = 0; j < 4; j++) {
            float4 t1 = *(const float4*)&Ybc[yb][0][roff + 4 * j];
            float4 t2 = *(const float4*)&Ybc[yb][1][roff + 4 * j];
            av1[2*j] = (f32x2){t1.x, t1.y}; av1[2*j+1] = (f32x2){t1.z, t1.w};
            av2[2*j] = (f32x2){t2.x, t2.y}; av2[2*j+1] = (f32x2){t2.z, t2.w};
        }

        f32x2 e11v = {0,0}, e21v = {0,0}, e22v = {0,0};
        #pragma unroll
        for (int j = 0; j < 8; j++) {
            e11v += av1[j] * k1[j];
            e21v += av1[j] * k2[j];
            e22v += av2[j] * k2[j];
        }
        float e11 = red8(e11v.x + e11v.y);
        float e21 = red8(e21v.x + e21v.y);
        float e22 = red8(e22v.x + e22v.y);

        #pragma unroll
        for (int j = 0; j < 4; j++) {
            float4 t1 = *(const float4*)&kst[nk][0][roff + 4 * j];
            float4 t2 = *(const float4*)&kst[nk][1][roff + 4 * j];
            k1[2*j] = (f32x2){t1.x, t1.y}; k1[2*j+1] = (f32x2){t1.z, t1.w};
            k2[2*j] = (f32x2){t2.x, t2.y}; k2[2*j+1] = (f32x2){t2.z, t2.w};
        }

        const float rn1 = rs_cur.x, rn2 = rs_cur.y;
        const float rn1sq = rn1 * rn1;
        const float rn2sq = rn2 * rn2;
        const float i1   = __builtin_amdgcn_rcpf(1.0f + rn1sq * e11);
        const float beta = rn1sq * e21 * i1;
        const float i2   = __builtin_amdgcn_rcpf(1.0f + rn2sq * (e22 - beta * e21));
        const float p2r0 = y2r0 - beta * y1r0;
        const float p2r1 = y2r1 - beta * y1r1;
        const float za1  = rn1 * i1;
        const float za2  = rn2 * i2;
        if (o8 == 0) {
            *(float2*)(Zb + (size_t)(2*i)     * HH + r0) =
                make_float2(za1 * y1r0, za1 * y1r1);
            *(float2*)(Zb + (size_t)(2*i + 1) * HH + r0) =
                make_float2(za2 * p2r0, za2 * p2r1);
        }

        const float cA1 = rn1sq * i1, cA2 = rn2sq * i2;
        const f32x2 u10 = {cA1 * y1r0, cA1 * y1r0};
        const f32x2 u11 = {cA1 * y1r1, cA1 * y1r1};
        const f32x2 u20 = {cA2 * p2r0, cA2 * p2r0};
        const f32x2 u21 = {cA2 * p2r1, cA2 * p2r1};
        const f32x2 bbv = {beta, beta};
        #pragma unroll
        for (int j = 0; j < 8; j++) {
            f32x2 pp = av2[j] - bbv * av1[j];
            Ar0[j] = Ar0[j] - u10 * av1[j] - u20 * pp;
            Ar1[j] = Ar1[j] - u11 * av1[j] - u21 * pp;
        }

        rs_cur = rs_nxt;
        if (i + 2 < NI) rs_nxt = ((const float2*)rn_b)[i + 2];
    }
}

// ---------------------------------------------------------------------------
// Phase 2a: G[b][c] = V_chunk^T @ (diag(s) Z_chunk). FULL-GPU: grid (64,4),
// 256 threads, 32 G-rows per block.
// ---------------------------------------------------------------------------
__global__ __launch_bounds__(256) void gram_kernel(
    const float* __restrict__ V, const float* __restrict__ Z,
    const float* __restrict__ Sarr, float* __restrict__ G)
{
    const int bi = blockIdx.x;                 // b*NCH + chunk
    const int r0 = blockIdx.y * 32;

    const float* Vc = V + (size_t)bi * CC * HH;
    const float* Zc = Z + (size_t)bi * CC * HH;
    const float* Sc = Sarr + (size_t)bi * CC;

    __shared__ float vT[32][36];
    __shared__ float aT[32][132];

    const int tid = threadIdx.x;
    const int tx = tid & 15, ty = tid >> 4;

    float acc[2][8];
    #pragma unroll
    for (int i = 0; i < 2; i++)
        #pragma unroll
        for (int j = 0; j < 8; j++) acc[i][j] = 0.f;

    for (int s0 = 0; s0 < CC; s0 += 32) {
        {   int sr = tid >> 3, rc = tid & 7;    // 32 s x 8 f4 (32 cols)
            float4 v = *(const float4*)(Vc + (size_t)(s0 + sr) * HH + r0 + rc * 4);
            *(float4*)&vT[sr][rc * 4] = v;
        }
        #pragma unroll
        for (int l = 0; l < 4; l++) {           // 32 s x 32 f4 (128 cols)
            int f = tid + l * 256;
            int sr = f >> 5, cc = f & 31;
            float sv = Sc[s0 + sr];
            float4 v = *(const float4*)(Zc + (size_t)(s0 + sr) * HH + cc * 4);
            v.x *= sv; v.y *= sv; v.z *= sv; v.w *= sv;
            *(float4*)&aT[sr][cc * 4] = v;
        }
        __syncthreads();
        #pragma unroll
        for (int ss = 0; ss < 32; ss++) {
            float2 vv = *(const float2*)&vT[ss][ty * 2];
            float4 a0 = *(const float4*)&aT[ss][tx * 8];
            float4 a1 = *(const float4*)&aT[ss][tx * 8 + 4];
            float va[2] = {vv.x, vv.y};
            float aa[8] = {a0.x, a0.y, a0.z, a0.w, a1.x, a1.y, a1.z, a1.w};
            #pragma unroll
            for (int i = 0; i < 2; i++)
                #pragma unroll
                for (int j = 0; j < 8; j++)
                    acc[i][j] += va[i] * aa[j];
        }
        __syncthreads();
    }

    #pragma unroll
    for (int i = 0; i < 2; i++) {
        float* gp = G + ((size_t)bi * HH + r0 + ty * 2 + i) * HH + tx * 8;
        float4 o0 = {acc[i][0], acc[i][1], acc[i][2], acc[i][3]};
        float4 o1 = {acc[i][4], acc[i][5], acc[i][6], acc[i][7]};
        *(float4*)gp       = o0;
        *(float4*)(gp + 4) = o1;
    }
}

// ---------------------------------------------------------------------------
// Phase 2b: exclusive prefix over chunks: Mpre[b][i] = sum_{j<i} G[b][j].
// ---------------------------------------------------------------------------
__global__ __launch_bounds__(256) void prefix_kernel(
    const float* __restrict__ G, float* __restrict__ Mpre)
{
    const int b   = blockIdx.x;
    const int idx = blockIdx.y * 256 + threadIdx.x;
    float run = 0.f;
    for (int i = 0; i < NCH; i++) {
        size_t off = ((size_t)b * NCH + i) * HH * HH + idx;
        Mpre[off] = run;
        run += G[off];
    }
}

// ---------------------------------------------------------------------------
// Phase 2c: O rows t0..t0+32 of chunk bi: Q Mpre^T + tril(Q (sZ)^T) V.
// FULL-GPU: grid (64,4), 256 threads, 32 t-rows per block.
// ---------------------------------------------------------------------------
__global__ __launch_bounds__(256) void ochunk_kernel(
    const float* __restrict__ Q, const float* __restrict__ Z,
    const float* __restrict__ Sarr, const float* __restrict__ V,
    const float* __restrict__ Mpre, float* __restrict__ O)
{
    const int bi = blockIdx.x;
    const int t0 = blockIdx.y * 32;            // local t base within chunk

    const float* Qc = Q    + (size_t)bi * CC * HH;
    const float* Zc = Z    + (size_t)bi * CC * HH;
    const float* Vc = V    + (size_t)bi * CC * HH;
    const float* Sc = Sarr + (size_t)bi * CC;
    const float* Mp = Mpre + (size_t)bi * HH * HH;
    float*       Oc = O    + (size_t)bi * CC * HH;

    __shared__ float S[32][132];
    __shared__ float xT[32][36];
    __shared__ float wT[32][132];

    const int tid = threadIdx.x;
    const int tx = tid & 15, ty = tid >> 4;    // ty 0..15, rows ty*2..+2

    float acc[2][8];

    // ---- phase 1: S = tril(Q (sZ)^T), K = h
    #pragma unroll
    for (int i = 0; i < 2; i++)
        #pragma unroll
        for (int j = 0; j < 8; j++) acc[i][j] = 0.f;
    for (int k0 = 0; k0 < HH; k0 += 32) {
        {   int r = tid >> 3, cg = tid & 7;
            float4 v = *(const float4*)(Qc + (size_t)(t0 + r) * HH + k0 + cg * 4);
            xT[cg*4+0][r] = v.x; xT[cg*4+1][r] = v.y;
            xT[cg*4+2][r] = v.z; xT[cg*4+3][r] = v.w;
        }
        #pragma unroll
        for (int l = 0; l < 4; l++) {
            int f = tid + l * 256;
            int sr = f >> 3, cg = f & 7;
            float sv = Sc[sr];
            float4 v = *(const float4*)(Zc + (size_t)sr * HH + k0 + cg * 4);
            wT[cg*4+0][sr] = v.x * sv; wT[cg*4+1][sr] = v.y * sv;
            wT[cg*4+2][sr] = v.z * sv; wT[cg*4+3][sr] = v.w * sv;
        }
        __syncthreads();
        #pragma unroll
        for (int kk = 0; kk < 32; kk++) {
            float2 xv = *(const float2*)&xT[kk][ty * 2];
            float4 w0 = *(const float4*)&wT[kk][tx * 8];
            float4 w1 = *(const float4*)&wT[kk][tx * 8 + 4];
            float xa[2] = {xv.x, xv.y};
            float wa[8] = {w0.x, w0.y, w0.z, w0.w, w1.x, w1.y, w1.z, w1.w};
            #pragma unroll
            for (int i = 0; i < 2; i++)
                #pragma unroll
                for (int j = 0; j < 8; j++)
                    acc[i][j] += xa[i] * wa[j];
        }
        __syncthreads();
    }
    #pragma unroll
    for (int i = 0; i < 2; i++) {
        int tl = t0 + ty * 2 + i;
        float m[8];
        #pragma unroll
        for (int j = 0; j < 8; j++)
            m[j] = (tx * 8 + j <= tl) ? acc[i][j] : 0.f;
        float4 o0 = {m[0], m[1], m[2], m[3]};
        float4 o1 = {m[4], m[5], m[6], m[7]};
        *(float4*)&S[ty*2+i][tx*8]     = o0;
        *(float4*)&S[ty*2+i][tx*8 + 4] = o1;
    }

    // ---- phase 2: acc = Q @ Mpre^T, K = h
    #pragma unroll
    for (int i = 0; i < 2; i++)
        #pragma unroll
        for (int j = 0; j < 8; j++) acc[i][j] = 0.f;
    for (int k0 = 0; k0 < HH; k0 += 32) {
        {   int r = tid >> 3, cg = tid & 7;
            float4 v = *(const float4*)(Qc + (size_t)(t0 + r) * HH + k0 + cg * 4);
            xT[cg*4+0][r] = v.x; xT[cg*4+1][r] = v.y;
            xT[cg*4+2][r] = v.z; xT[cg*4+3][r] = v.w;
        }
        #pragma unroll
        for (int l = 0; l < 4; l++) {
            int f = tid + l * 256;
            int h = f >> 3, cg = f & 7;
            float4 v = *(const float4*)(Mp + (size_t)h * HH + k0 + cg * 4);
            wT[cg*4+0][h] = v.x; wT[cg*4+1][h] = v.y;
            wT[cg*4+2][h] = v.z; wT[cg*4+3][h] = v.w;
        }
        __syncthreads();
        #pragma unroll
        for (int kk = 0; kk < 32; kk++) {
            float2 xv = *(const float2*)&xT[kk][ty * 2];
            float4 w0 = *(const float4*)&wT[kk][tx * 8];
            float4 w1 = *(const float4*)&wT[kk][tx * 8 + 4];
            float xa[2] = {xv.x, xv.y};
            float wa[8] = {w0.x, w0.y, w0.z, w0.w, w1.x, w1.y, w1.z, w1.w};
            #pragma unroll
            for (int i = 0; i < 2; i++)
                #pragma unroll
                for (int j = 0; j < 8; j++)
                    acc[i][j] += xa[i] * wa[j];
        }
        __syncthreads();
    }

    // ---- phase 3: acc += S @ V, K = s
    for (int s0 = 0; s0 < CC; s0 += 32) {
        #pragma unroll
        for (int l = 0; l < 4; l++) {
            int f = tid + l * 256;
            int sr = f >> 5, cc = f & 31;
            float4 v = *(const float4*)(Vc + (size_t)(s0 + sr) * HH + cc * 4);
            *(float4*)&wT[sr][cc * 4] = v;
        }
        __syncthreads();
        #pragma unroll
        for (int ss = 0; ss < 32; ss++) {
            float4 w0 = *(const float4*)&wT[ss][tx * 8];
            float4 w1 = *(const float4*)&wT[ss][tx * 8 + 4];
            float wa[8] = {w0.x, w0.y, w0.z, w0.w, w1.x, w1.y, w1.z, w1.w};
            float sv[2] = {S[ty*2][s0 + ss], S[ty*2+1][s0 + ss]};
            #pragma unroll
            for (int i = 0; i < 2; i++)
                #pragma unroll
                for (int j = 0; j < 8; j++)
                    acc[i][j] += sv[i] * wa[j];
        }
        __syncthreads();
    }

    #pragma unroll
    for (int i = 0; i < 2; i++) {
        float* op = Oc + (size_t)(t0 + ty * 2 + i) * HH + tx * 8;
        float4 o0 = {acc[i][0], acc[i][1], acc[i][2], acc[i][3]};
        float4 o1 = {acc[i][4], acc[i][5], acc[i][6], acc[i][7]};
        *(float4*)op       = o0;
        *(float4*)(op + 4) = o1;
    }
}

// ---------------------------------------------------------------------------
// Output: out[bt][d] = sum_h O[bt][h] * Wo[d][h] + bo[d]
// ---------------------------------------------------------------------------
__global__ __launch_bounds__(256) void out_kernel(
    const float* __restrict__ O, const float* __restrict__ Wo,
    const float* __restrict__ bo, float* __restrict__ out)
{
    const int row0 = blockIdx.x * 64;
    const int d0   = blockIdx.y * 128;

    __shared__ float oT[32][68];
    __shared__ float woT[32][132];

    const int tid = threadIdx.x;
    const int tx = tid & 15;
    const int ty = tid >> 4;

    float acc[4][8];
    #pragma unroll
    for (int i = 0; i < 4; i++)
        #pragma unroll
        for (int j = 0; j < 8; j++) acc[i][j] = 0.f;

    for (int k0 = 0; k0 < HH; k0 += 32) {
        #pragma unroll
        for (int l = 0; l < 2; l++) {
            int f = tid + l * 256;
            int r = f >> 3;
            int cg = f & 7;
            float4 v = *(const float4*)(O + (size_t)(row0 + r) * HH + k0 + cg * 4);
            oT[cg*4+0][r] = v.x; oT[cg*4+1][r] = v.y;
            oT[cg*4+2][r] = v.z; oT[cg*4+3][r] = v.w;
        }
        #pragma unroll
        for (int l = 0; l < 4; l++) {
            int f = tid + l * 256;
            int d = f >> 3;
            int cg = f & 7;
            float4 v = *(const float4*)(Wo + (size_t)(d0 + d) * HH + k0 + cg * 4);
            woT[cg*4+0][d] = v.x; woT[cg*4+1][d] = v.y;
            woT[cg*4+2][d] = v.z; woT[cg*4+3][d] = v.w;
        }
        __syncthreads();
        #pragma unroll
        for (int kk = 0; kk < 32; kk++) {
            float4 ov = *(const float4*)&oT[kk][ty * 4];
            float4 w0 = *(const float4*)&woT[kk][tx * 8];
            float4 w1 = *(const float4*)&woT[kk][tx * 8 + 4];
            float oa[4] = {ov.x, ov.y, ov.z, ov.w};
            float wa[8] = {w0.x, w0.y, w0.z, w0.w, w1.x, w1.y, w1.z, w1.w};
            #pragma unroll
            for (int i = 0; i < 4; i++)
                #pragma unroll
                for (int j = 0; j < 8; j++)
                    acc[i][j] += oa[i] * wa[j];
        }
        __syncthreads();
    }

    #pragma unroll
    for (int i = 0; i < 4; i++) {
        int row = row0 + ty * 4 + i;
        #pragma unroll
        for (int j = 0; j < 8; j++) acc[i][j] += bo[d0 + tx * 8 + j];
        float4 o0 = {acc[i][0], acc[i][1], acc[i][2], acc[i][3]};
        float4 o1 = {acc[i][4], acc[i][5], acc[i][6], acc[i][7]};
        *(float4*)(out + (size_t)row * DD + d0 + tx * 8)     = o0;
        *(float4*)(out + (size_t)row * DD + d0 + tx * 8 + 4) = o1;
    }
}

extern "C" void kernel_launch(void* const* d_in, const int* in_sizes, int n_in,
                              void* d_out, int out_size, void* d_ws, size_t ws_size,
                              hipStream_t stream) {
    const float* x  = (const float*)d_in[0];
    const float* Wq = (const float*)d_in[1];
    const float* bq = (const float*)d_in[2];
    const float* Wk = (const float*)d_in[3];
    const float* bk = (const float*)d_in[4];
    const float* Wv = (const float*)d_in[5];
    const float* bv = (const float*)d_in[6];
    const float* Wo = (const float*)d_in[7];
    const float* bo = (const float*)d_in[8];
    float* out = (float*)d_out;

    float* ws = (float*)d_ws;
    float* Q = ws;
    float* K = ws + (size_t)BT * HH;
    float* V = ws + (size_t)2 * BT * HH;
    float* O = ws + (size_t)3 * BT * HH;

    // scratch in d_out (32 MB), all dead before out_kernel writes it:
    //   rn @0 (32KB) | s @32KB | Z @1MB (4MB) | G @8MB (4MB) | Mpre @12MB (4MB)
    float* db   = (float*)d_out;
    float* rn   = db;
    float* Sarr = db + BT;
    float* Z    = db + (1u << 18);
    float* G    = db + (1u << 21);
    float* Mpre = db + 3u * (1u << 20);

    // 1. K projection (+rn) — full-GPU 256 blocks
    projk_kernel<<<BT / 32, 256, 0, stream>>>(x, Wk, bk, K, rn);

    // 2. fused: 4 scan blocks + 252 worker blocks (Q proj + s, V proj)
    fused_kernel<<<256, 512, 0, stream>>>(
        x, Wq, bq, Wv, bv, K, rn, Q, V, Sarr, Z);

    // 3. chunked phase-2 (alpha = s*z folded into staging), full-GPU grids
    dim3 ggrid(BB * NCH, 4);
    gram_kernel<<<ggrid, 256, 0, stream>>>(V, Z, Sarr, G);

    dim3 fgrid(BB, HH * HH / 256);
    prefix_kernel<<<fgrid, 256, 0, stream>>>(G, Mpre);

    dim3 cgrid(BB * NCH, 4);
    ochunk_kernel<<<cgrid, 256, 0, stream>>>(Q, Z, Sarr, V, Mpre, O);

    dim3 ogrid(BT / 64, DD / 128);
    out_kernel<<<ogrid, 256, 0, stream>>>(O, Wo, bo, out);
}